// Round 1
// baseline (117.257 us; speedup 1.0000x reference)
//
#include <hip/hip_runtime.h>
#include <hip/hip_bf16.h>

// Problem constants (from reference): B=1024, F=33, D=128, A=128, P=F*(F-1)/2=528
#define FN 33
#define DN 128
#define AN 128
#define PN 528
#define MTN 33     // P / 16 M-tiles, exact
#define XS 136     // bf16 row stride for x/W in LDS (136*2=272B, 16B-aligned, +8 pad breaks pow2)
#define TS 36      // float row stride for xT / attn2d (144B, 16B-aligned)

typedef __attribute__((ext_vector_type(8))) short short8;   // 8 bf16 (4 VGPRs) MFMA frag
typedef __attribute__((ext_vector_type(4))) float f32x4;
typedef __attribute__((ext_vector_type(4))) int i32x4;

union V4 { i32x4 i; short8 s; f32x4 f; };

__device__ __forceinline__ float bitf(unsigned int u) { return __builtin_bit_cast(float, u); }
__device__ __forceinline__ unsigned int fbits(float f) { return __builtin_bit_cast(unsigned int, f); }

// pack two f32 -> bf16x2 dword (round-half-up via +0x8000 on the bit pattern, then byte-perm)
__device__ __forceinline__ unsigned int pack2_bf16(float lo, float hi) {
  unsigned int ul = fbits(lo) + 0x8000u;
  unsigned int uh = fbits(hi) + 0x8000u;
  // dst = [uh.b3, uh.b2, ul.b3, ul.b2]  (low16 = bf16(lo))
  return __builtin_amdgcn_perm(uh, ul, 0x07060302);
}

__global__ __launch_bounds__(256, 2)
void afm_kernel(const float* __restrict__ gnn, const float* __restrict__ xg,
                const float* __restrict__ Wg,  const float* __restrict__ bg,
                float* __restrict__ out)
{
  __shared__ __align__(16) unsigned short Wl[AN * XS];   // W as bf16 bits, row-major [a][d]
  __shared__ __align__(16) unsigned short xb[FN * XS];   // x[b] as bf16 bits, [i][d]
  __shared__ __align__(16) float xT[DN * TS];            // x[b] fp32 transposed [d][i]
  __shared__ __align__(16) float attn2d[FN * TS];        // unnormalized exp, row i = pairs (i, i+1+jj)
  __shared__ __align__(16) float scores_s[PN];
  __shared__ float gnn_s[AN];
  __shared__ float bias_s[AN];
  __shared__ unsigned short rowcol[PN];                  // i | (j<<8)
  __shared__ float red[8];

  const int tid  = threadIdx.x;
  const int b    = blockIdx.x;
  const int wave = tid >> 6;
  const int lane = tid & 63;
  const int q    = lane >> 4;   // quad 0..3
  const int u    = lane & 15;

  // ---------------- staging ----------------
  for (int idx = tid; idx < FN * TS; idx += 256) attn2d[idx] = 0.0f;

  const f32x4* xg4 = (const f32x4*)(xg + (size_t)b * FN * DN);
  for (int idx = tid; idx < (FN * DN) / 4; idx += 256) {   // 1056 float4
    f32x4 v = xg4[idx];
    int i  = idx >> 5;           // row (d stride 128 = 32 float4)
    int d0 = (idx & 31) << 2;
    unsigned int lo = pack2_bf16(v.x, v.y);
    unsigned int hi = pack2_bf16(v.z, v.w);
    *(uint2*)&xb[i * XS + d0] = make_uint2(lo, hi);
    xT[(d0 + 0) * TS + i] = v.x;
    xT[(d0 + 1) * TS + i] = v.y;
    xT[(d0 + 2) * TS + i] = v.z;
    xT[(d0 + 3) * TS + i] = v.w;
  }
  if (tid < DN) {  // zero xT pad columns (epilogue reads up to i=35; avoid NaN garbage)
    xT[tid * TS + 33] = 0.f; xT[tid * TS + 34] = 0.f; xT[tid * TS + 35] = 0.f;
  }

  const f32x4* Wg4 = (const f32x4*)Wg;
  for (int idx = tid; idx < (AN * DN) / 4; idx += 256) {   // 4096 float4
    f32x4 v = Wg4[idx];
    int a  = idx >> 5;
    int d0 = (idx & 31) << 2;
    *(uint2*)&Wl[a * XS + d0] = make_uint2(pack2_bf16(v.x, v.y), pack2_bf16(v.z, v.w));
  }
  if (tid < AN) {
    gnn_s[tid]  = gnn[(size_t)b * AN + tid];
    bias_s[tid] = bg[tid];
  }
  for (int p = tid; p < PN; p += 256) {
    int i = 0, rem = p;
    while (rem >= FN - 1 - i) { rem -= FN - 1 - i; i++; }
    rowcol[p] = (unsigned short)(i | ((i + 1 + rem) << 8));
  }
  __syncthreads();

  // ---------------- fm matmul + score (MFMA) ----------------
  // B-frags cached in registers: B[k][n] = W[n0+n][k]; lane holds W[n*16+u][kk*32+q*8 .. +7]
  V4 Bf[8][4];
  #pragma unroll
  for (int n = 0; n < 8; n++)
    #pragma unroll
    for (int kk = 0; kk < 4; kk++)
      Bf[n][kk].i = *(const i32x4*)&Wl[(n * 16 + u) * XS + kk * 32 + q * 8];

  float garr[8], barr[8];
  #pragma unroll
  for (int n = 0; n < 8; n++) { garr[n] = gnn_s[n * 16 + u]; barr[n] = bias_s[n * 16 + u]; }

  for (int mt = wave; mt < MTN; mt += 4) {
    const int p = mt * 16 + u;
    const unsigned int rc = rowcol[p];
    const int r = rc & 255, c = rc >> 8;

    V4 Af[4];  // A[m=u][k=kk*32+q*8+j] = inner[p][k] = x[r][k]*x[c][k]
    #pragma unroll
    for (int kk = 0; kk < 4; kk++) {
      i32x4 xr = *(const i32x4*)&xb[r * XS + kk * 32 + q * 8];
      i32x4 xc = *(const i32x4*)&xb[c * XS + kk * 32 + q * 8];
      i32x4 o;
      #pragma unroll
      for (int t = 0; t < 4; t++) {
        unsigned int ar = (unsigned int)xr[t], ac = (unsigned int)xc[t];
        float flo = bitf(ar << 16) * bitf(ac << 16);
        float fhi = bitf(ar & 0xffff0000u) * bitf(ac & 0xffff0000u);
        o[t] = (int)pack2_bf16(flo, fhi);
      }
      Af[kk].i = o;
    }

    f32x4 acc[8];
    #pragma unroll
    for (int n = 0; n < 8; n++) acc[n] = (f32x4){0.f, 0.f, 0.f, 0.f};
    #pragma unroll
    for (int kk = 0; kk < 4; kk++)
      #pragma unroll
      for (int n = 0; n < 8; n++)
        acc[n] = __builtin_amdgcn_mfma_f32_16x16x32_bf16(Af[kk].s, Bf[n][kk].s, acc[n], 0, 0, 0);

    // fused bias + relu + gnn dot: D[row=q*4+rr][col=u], a = n*16+u
    float sc[4] = {0.f, 0.f, 0.f, 0.f};
    #pragma unroll
    for (int n = 0; n < 8; n++)
      #pragma unroll
      for (int rr = 0; rr < 4; rr++) {
        float fmv = acc[n][rr] + barr[n];
        fmv = fmv > 0.f ? fmv : 0.f;
        sc[rr] = fmaf(fmv, garr[n], sc[rr]);
      }
    // reduce over the 16 col-lanes (u bits)
    #pragma unroll
    for (int off = 1; off < 16; off <<= 1)
      #pragma unroll
      for (int rr = 0; rr < 4; rr++)
        sc[rr] += __shfl_xor(sc[rr], off, 64);
    if (u == 0)
      *(f32x4*)&scores_s[mt * 16 + q * 4] = (f32x4){sc[0], sc[1], sc[2], sc[3]};
  }
  __syncthreads();

  // ---------------- softmax over 528 scores ----------------
  float s0 = scores_s[tid];
  float s1 = scores_s[tid + 256];
  float s2 = (tid < 16) ? scores_s[tid + 512] : -3.4e38f;
  float m = fmaxf(fmaxf(s0, s1), s2);
  #pragma unroll
  for (int off = 32; off >= 1; off >>= 1) m = fmaxf(m, __shfl_xor(m, off, 64));
  if (lane == 0) red[wave] = m;
  __syncthreads();
  const float smax = fmaxf(fmaxf(red[0], red[1]), fmaxf(red[2], red[3]));

  float e0 = __expf(s0 - smax);
  float e1 = __expf(s1 - smax);
  float e2 = (tid < 16) ? __expf(s2 - smax) : 0.f;
  {
    unsigned int rc = rowcol[tid];
    attn2d[(rc & 255) * TS + ((rc >> 8) - (rc & 255) - 1)] = e0;
    rc = rowcol[tid + 256];
    attn2d[(rc & 255) * TS + ((rc >> 8) - (rc & 255) - 1)] = e1;
    if (tid < 16) {
      rc = rowcol[tid + 512];
      attn2d[(rc & 255) * TS + ((rc >> 8) - (rc & 255) - 1)] = e2;
    }
  }
  float lsum = e0 + e1 + e2;
  #pragma unroll
  for (int off = 32; off >= 1; off >>= 1) lsum += __shfl_xor(lsum, off, 64);
  if (lane == 0) red[4 + wave] = lsum;
  __syncthreads();
  const float Z = red[4] + red[5] + red[6] + red[7];

  // ---------------- epilogue: out = [gnn, 100 * attn @ inner] ----------------
  if (tid < DN) {
    const int d = tid;
    float xcol[36];
    #pragma unroll
    for (int t = 0; t < 9; t++) {
      f32x4 v = *(const f32x4*)&xT[d * TS + t * 4];
      xcol[t * 4 + 0] = v.x; xcol[t * 4 + 1] = v.y;
      xcol[t * 4 + 2] = v.z; xcol[t * 4 + 3] = v.w;
    }
    float acc = 0.f;
    #pragma unroll
    for (int i = 0; i < FN - 1; i++) {          // i = 0..31
      const int L = FN - 1 - i;                 // pairs (i, i+1+jj), jj < L
      const int nf4 = (L + 3) >> 2;
      float ti = 0.f;
      #pragma unroll
      for (int t = 0; t < nf4; t++) {
        f32x4 a4 = *(const f32x4*)&attn2d[i * TS + t * 4];  // pad entries are 0
        ti = fmaf(a4.x, xcol[i + 1 + t * 4 + 0], ti);
        ti = fmaf(a4.y, xcol[i + 1 + t * 4 + 1], ti);
        ti = fmaf(a4.z, xcol[i + 1 + t * 4 + 2], ti);
        ti = fmaf(a4.w, xcol[i + 1 + t * 4 + 3], ti);
      }
      acc = fmaf(xcol[i], ti, acc);
    }
    out[(size_t)b * (AN + DN) + AN + d] = acc * (100.0f / Z);
  } else {
    const int a = tid - 128;
    out[(size_t)b * (AN + DN) + a] = gnn_s[a];
  }
}

extern "C" void kernel_launch(void* const* d_in, const int* in_sizes, int n_in,
                              void* d_out, int out_size, void* d_ws, size_t ws_size,
                              hipStream_t stream) {
  (void)n_in; (void)out_size; (void)d_ws; (void)ws_size;
  const float* gnn  = (const float*)d_in[0];
  const float* x    = (const float*)d_in[1];
  const float* W    = (const float*)d_in[2];
  const float* bias = (const float*)d_in[3];
  float* out = (float*)d_out;
  const int Bn = in_sizes[0] / AN;   // 1024
  afm_kernel<<<dim3(Bn), dim3(256), 0, stream>>>(gnn, x, W, bias, out);
}

// Round 3
// 116.533 us; speedup vs baseline: 1.0062x; 1.0062x over previous
//
#include <hip/hip_runtime.h>

// Problem constants: B=1024, F=33, D=128, A=128, P=F*(F-1)/2=528
#define FN 33
#define DN 128
#define AN 128
#define PN 528
#define MTN 33     // P / 16 M-tiles, exact
#define XS 136     // fp16 row stride for xh in LDS (272 B, 16B-aligned, non-pow2)
#define TS 36      // float row stride for attn2d (144 B)

typedef __attribute__((ext_vector_type(8))) _Float16 half8;
typedef __attribute__((ext_vector_type(4))) float f32x4;

// f32x2 -> packed fp16 dword (v_cvt_pkrtz_f16_f32); bit_cast immediately to
// avoid __fp16-vs-_Float16 vector type clashes.
__device__ __forceinline__ unsigned int pkrtz(float a, float b) {
  return __builtin_bit_cast(unsigned int, __builtin_amdgcn_cvt_pkrtz(a, b));
}

// sum over the 16-lane DPP row via row_ror rotations (VALU pipe, no LDS)
__device__ __forceinline__ float row_sum16(float v) {
  v += __builtin_bit_cast(float, __builtin_amdgcn_update_dpp(0, __builtin_bit_cast(int, v), 0x128, 0xF, 0xF, false));
  v += __builtin_bit_cast(float, __builtin_amdgcn_update_dpp(0, __builtin_bit_cast(int, v), 0x124, 0xF, 0xF, false));
  v += __builtin_bit_cast(float, __builtin_amdgcn_update_dpp(0, __builtin_bit_cast(int, v), 0x122, 0xF, 0xF, false));
  v += __builtin_bit_cast(float, __builtin_amdgcn_update_dpp(0, __builtin_bit_cast(int, v), 0x121, 0xF, 0xF, false));
  return v;
}

__global__ __launch_bounds__(256, 2)
void afm_kernel(const float* __restrict__ gnn, const float* __restrict__ xg,
                const float* __restrict__ Wg,  const float* __restrict__ bg,
                float* __restrict__ out)
{
  __shared__ __align__(16) _Float16 xh[FN * XS];        // x[b] as fp16, [i][d]
  __shared__ __align__(16) float attn2d[FN * TS];       // unnormalized exp, row i = pairs (i, i+1+jj)
  __shared__ __align__(16) float scores_s[PN];
  __shared__ __align__(16) float part[256];             // epilogue partials
  __shared__ unsigned short rowcol[PN];                 // i | (j<<8)
  __shared__ float red[8];

  const int tid  = threadIdx.x;
  const int b    = blockIdx.x;
  const int wave = tid >> 6;
  const int lane = tid & 63;
  const int q    = lane >> 4;   // quad 0..3
  const int u    = lane & 15;

  // ---------------- staging ----------------
  for (int idx = tid; idx < FN * TS; idx += 256) attn2d[idx] = 0.0f;

  const f32x4* xg4 = (const f32x4*)(xg + (size_t)b * FN * DN);
  for (int idx = tid; idx < (FN * DN) / 4; idx += 256) {   // 1056 float4
    f32x4 v = xg4[idx];
    int i  = idx >> 5;           // field row
    int d0 = (idx & 31) << 2;
    *(uint2*)&xh[i * XS + d0] = make_uint2(pkrtz(v.x, v.y), pkrtz(v.z, v.w));
  }
  for (int p = tid; p < PN; p += 256) {
    int i = 0, rem = p;
    while (rem >= FN - 1 - i) { rem -= FN - 1 - i; i++; }
    rowcol[p] = (unsigned short)(i | ((i + 1 + rem) << 8));
  }

  // ---------------- B-fragments from global W (L2-resident, fp32 -> fp16) ----------------
  // Bf[n][kk]: lane holds W[a = n*16+u][k = kk*32 + q*8 .. +7]
  half8 Bf[8][4];
  #pragma unroll
  for (int n = 0; n < 8; n++) {
    const float* wrow = Wg + (size_t)(n * 16 + u) * DN + q * 8;
    #pragma unroll
    for (int kk = 0; kk < 4; kk++) {
      f32x4 w0 = *(const f32x4*)(wrow + kk * 32);
      f32x4 w1 = *(const f32x4*)(wrow + kk * 32 + 4);
      union { half8 h; unsigned int w[4]; } t;
      t.w[0] = pkrtz(w0.x, w0.y);
      t.w[1] = pkrtz(w0.z, w0.w);
      t.w[2] = pkrtz(w1.x, w1.y);
      t.w[3] = pkrtz(w1.z, w1.w);
      Bf[n][kk] = t.h;
    }
  }
  float garr[8], barr[8];
  #pragma unroll
  for (int n = 0; n < 8; n++) {
    garr[n] = gnn[(size_t)b * AN + n * 16 + u];
    barr[n] = bg[n * 16 + u];
  }
  __syncthreads();

  // ---------------- fm matmul + score (fp16 MFMA, m-split over waves) ----------------
  for (int mt = wave; mt < MTN; mt += 4) {
    const int p = mt * 16 + u;
    const unsigned int rc = rowcol[p];
    const int r = rc & 255, c = rc >> 8;

    half8 Af[4];  // A[m=u][k=kk*32+q*8+j] = x[r][k]*x[c][k]
    #pragma unroll
    for (int kk = 0; kk < 4; kk++) {
      half8 xr = *(const half8*)&xh[r * XS + kk * 32 + q * 8];
      half8 xc = *(const half8*)&xh[c * XS + kk * 32 + q * 8];
      Af[kk] = xr * xc;                        // 4x v_pk_mul_f16
    }

    f32x4 acc[8];
    #pragma unroll
    for (int n = 0; n < 8; n++) acc[n] = (f32x4){0.f, 0.f, 0.f, 0.f};
    #pragma unroll
    for (int kk = 0; kk < 4; kk++)
      #pragma unroll
      for (int n = 0; n < 8; n++)
        acc[n] = __builtin_amdgcn_mfma_f32_16x16x32_f16(Af[kk], Bf[n][kk], acc[n], 0, 0, 0);

    // fused bias + relu + gnn dot: D[row=q*4+rr][col=u], a = n*16+u
    float sc[4] = {0.f, 0.f, 0.f, 0.f};
    #pragma unroll
    for (int n = 0; n < 8; n++)
      #pragma unroll
      for (int rr = 0; rr < 4; rr++) {
        float fmv = acc[n][rr] + barr[n];
        fmv = fmv > 0.f ? fmv : 0.f;
        sc[rr] = fmaf(fmv, garr[n], sc[rr]);
      }
    #pragma unroll
    for (int rr = 0; rr < 4; rr++) sc[rr] = row_sum16(sc[rr]);
    if (u == 0)
      *(f32x4*)&scores_s[mt * 16 + q * 4] = (f32x4){sc[0], sc[1], sc[2], sc[3]};
  }
  __syncthreads();

  // ---------------- softmax over 528 scores ----------------
  float s0 = scores_s[tid];
  float s1 = scores_s[tid + 256];
  float s2 = (tid < 16) ? scores_s[tid + 512] : -3.4e38f;
  float m = fmaxf(fmaxf(s0, s1), s2);
  #pragma unroll
  for (int off = 32; off >= 1; off >>= 1) m = fmaxf(m, __shfl_xor(m, off, 64));
  if (lane == 0) red[wave] = m;
  __syncthreads();
  const float smax = fmaxf(fmaxf(red[0], red[1]), fmaxf(red[2], red[3]));

  float e0 = __expf(s0 - smax);
  float e1 = __expf(s1 - smax);
  float e2 = (tid < 16) ? __expf(s2 - smax) : 0.f;
  {
    unsigned int rc = rowcol[tid];
    attn2d[(rc & 255) * TS + ((rc >> 8) - (rc & 255) - 1)] = e0;
    rc = rowcol[tid + 256];
    attn2d[(rc & 255) * TS + ((rc >> 8) - (rc & 255) - 1)] = e1;
    if (tid < 16) {
      rc = rowcol[tid + 512];
      attn2d[(rc & 255) * TS + ((rc >> 8) - (rc & 255) - 1)] = e2;
    }
  }
  float lsum = e0 + e1 + e2;
  #pragma unroll
  for (int off = 32; off >= 1; off >>= 1) lsum += __shfl_xor(lsum, off, 64);
  if (lane == 0) red[4 + wave] = lsum;
  __syncthreads();
  const float Z = red[4] + red[5] + red[6] + red[7];

  // ---------------- epilogue: out = [gnn, 100 * attn @ inner], 2-way i-split ----------------
  {
    const int d = tid & 127;
    const int h = tid >> 7;          // i-range half
    float xcol[36];
    #pragma unroll
    for (int i = 0; i < FN; i++) xcol[i] = (float)xh[i * XS + d];
    xcol[33] = 0.f; xcol[34] = 0.f; xcol[35] = 0.f;

    float acc = 0.f;
    const int ibeg = h * 16, iend = ibeg + 16;   // i in [0,32)
    #pragma unroll
    for (int i = 0; i < 32; i++) {
      if (i < ibeg || i >= iend) continue;
      const int L = FN - 1 - i;                  // pairs (i, i+1+jj), jj < L
      const int nf4 = (L + 3) >> 2;
      float ti = 0.f;
      #pragma unroll
      for (int t = 0; t < 8; t++) {
        if (t >= nf4) break;
        f32x4 a4 = *(const f32x4*)&attn2d[i * TS + t * 4];  // pad entries are 0
        ti = fmaf(a4.x, xcol[i + 1 + t * 4 + 0], ti);
        ti = fmaf(a4.y, xcol[i + 1 + t * 4 + 1], ti);
        ti = fmaf(a4.z, xcol[i + 1 + t * 4 + 2], ti);
        ti = fmaf(a4.w, xcol[i + 1 + t * 4 + 3], ti);
      }
      acc = fmaf(xcol[i], ti, acc);
    }
    part[tid] = acc;
  }
  __syncthreads();
  if (tid < DN) {
    float tot = part[tid] + part[tid + 128];
    out[(size_t)b * (AN + DN) + AN + tid] = tot * (100.0f / Z);
  } else {
    const int a = tid - 128;
    out[(size_t)b * (AN + DN) + a] = gnn[(size_t)b * AN + a];
  }
}

extern "C" void kernel_launch(void* const* d_in, const int* in_sizes, int n_in,
                              void* d_out, int out_size, void* d_ws, size_t ws_size,
                              hipStream_t stream) {
  (void)n_in; (void)out_size; (void)d_ws; (void)ws_size;
  const float* gnn  = (const float*)d_in[0];
  const float* x    = (const float*)d_in[1];
  const float* W    = (const float*)d_in[2];
  const float* bias = (const float*)d_in[3];
  float* out = (float*)d_out;
  const int Bn = in_sizes[0] / AN;   // 1024
  afm_kernel<<<dim3(Bn), dim3(256), 0, stream>>>(gnn, x, W, bias, out);
}

// Round 4
// 108.330 us; speedup vs baseline: 1.0824x; 1.0757x over previous
//
#include <hip/hip_runtime.h>

// Problem constants: B=1024, F=33, D=128, A=128, P=F*(F-1)/2=528
#define FN 33
#define DN 128
#define AN 128
#define PN 528
#define MTN 33     // P / 16 M-tiles, exact
#define XS 136     // fp16 row stride for xh in LDS (272 B, 16B-aligned, non-pow2)
#define TS 36      // float row stride for attn2d (144 B)

typedef __attribute__((ext_vector_type(8))) _Float16 half8;
typedef __attribute__((ext_vector_type(4))) float f32x4;
typedef __attribute__((ext_vector_type(4))) unsigned int u32x4;

// f32x2 -> packed fp16 dword (v_cvt_pkrtz_f16_f32); bit_cast immediately to
// avoid __fp16-vs-_Float16 vector type clashes.
__device__ __forceinline__ unsigned int pkrtz(float a, float b) {
  return __builtin_bit_cast(unsigned int, __builtin_amdgcn_cvt_pkrtz(a, b));
}

// sum over the 16-lane DPP row via row_ror rotations (VALU pipe, no LDS)
__device__ __forceinline__ float row_sum16(float v) {
  v += __builtin_bit_cast(float, __builtin_amdgcn_update_dpp(0, __builtin_bit_cast(int, v), 0x128, 0xF, 0xF, false));
  v += __builtin_bit_cast(float, __builtin_amdgcn_update_dpp(0, __builtin_bit_cast(int, v), 0x124, 0xF, 0xF, false));
  v += __builtin_bit_cast(float, __builtin_amdgcn_update_dpp(0, __builtin_bit_cast(int, v), 0x122, 0xF, 0xF, false));
  v += __builtin_bit_cast(float, __builtin_amdgcn_update_dpp(0, __builtin_bit_cast(int, v), 0x121, 0xF, 0xF, false));
  return v;
}

__global__ __launch_bounds__(256, 2)
void afm_kernel(const float* __restrict__ gnn, const float* __restrict__ xg,
                const float* __restrict__ Wg,  const float* __restrict__ bg,
                float* __restrict__ out)
{
  // W fragments in chunk order: chunk C = ((n*4+kk)*4+q)*16+u holds 8 halves
  // = W[n*16+u][kk*32+q*8 .. +8] -> B-frag build is lane-sequential b128.
  __shared__ __align__(16) _Float16 Wl[2048 * 8];       // 32 KB
  __shared__ __align__(16) _Float16 xh[FN * XS];        // x[b] as fp16, [i][d]
  __shared__ __align__(16) float attn2d[FN * TS];       // unnormalized exp, row i = pairs (i, i+1+jj)
  __shared__ __align__(16) float scores_s[PN];
  __shared__ __align__(16) float part[256];             // epilogue partials
  __shared__ unsigned short rowcol[PN];                 // i | (j<<8)
  __shared__ float red[8];

  const int tid  = threadIdx.x;
  const int b    = blockIdx.x;
  const int wave = tid >> 6;
  const int lane = tid & 63;
  const int q    = lane >> 4;   // quad 0..3
  const int u    = lane & 15;

  // ---------------- staging ----------------
  for (int idx = tid; idx < FN * TS; idx += 256) attn2d[idx] = 0.0f;

  const f32x4* xg4 = (const f32x4*)(xg + (size_t)b * FN * DN);
  for (int idx = tid; idx < (FN * DN) / 4; idx += 256) {   // 1056 float4
    f32x4 v = xg4[idx];
    int i  = idx >> 5;           // field row
    int d0 = (idx & 31) << 2;
    *(uint2*)&xh[i * XS + d0] = make_uint2(pkrtz(v.x, v.y), pkrtz(v.z, v.w));
  }
  // W -> LDS chunks (fp16), 8 chunks per thread, conflict-free 16B stores
  #pragma unroll
  for (int s = 0; s < 8; s++) {
    int C  = tid + s * 256;           // 0..2047
    int n  = C >> 8;
    int kk = (C >> 6) & 3;
    int qq = (C >> 4) & 3;
    int uu = C & 15;
    const float* src = Wg + (size_t)(n * 16 + uu) * DN + kk * 32 + qq * 8;
    f32x4 w0 = *(const f32x4*)(src);
    f32x4 w1 = *(const f32x4*)(src + 4);
    u32x4 pk;
    pk.x = pkrtz(w0.x, w0.y);
    pk.y = pkrtz(w0.z, w0.w);
    pk.z = pkrtz(w1.x, w1.y);
    pk.w = pkrtz(w1.z, w1.w);
    *(u32x4*)&Wl[C * 8] = pk;
  }
  for (int p = tid; p < PN; p += 256) {
    int i = 0, rem = p;
    while (rem >= FN - 1 - i) { rem -= FN - 1 - i; i++; }
    rowcol[p] = (unsigned short)(i | ((i + 1 + rem) << 8));
  }
  __syncthreads();

  // ---------------- B-fragments from LDS, pinned in registers ----------------
  // Bf[n][kk]: lane holds W[a = n*16+u][k = kk*32 + q*8 .. +7]
  half8 Bf[8][4];
  #pragma unroll
  for (int n = 0; n < 8; n++)
    #pragma unroll
    for (int kk = 0; kk < 4; kk++) {
      Bf[n][kk] = *(const half8*)&Wl[((n * 4 + kk) * 64 + lane) * 8];
      asm volatile("" : "+v"(Bf[n][kk]));   // pin: forbid remat/sinking of the load
    }
  float garr[8], barr[8];
  #pragma unroll
  for (int n = 0; n < 8; n++) {
    garr[n] = gnn[(size_t)b * AN + n * 16 + u];
    barr[n] = bg[n * 16 + u];
    asm volatile("" : "+v"(garr[n]), "+v"(barr[n]));
  }

  // ---------------- fm matmul + score (fp16 MFMA, m-split over waves) ----------------
  for (int mt = wave; mt < MTN; mt += 4) {
    const int p = mt * 16 + u;
    const unsigned int rc = rowcol[p];
    const int r = rc & 255, c = rc >> 8;

    half8 Af[4];  // A[m=u][k=kk*32+q*8+j] = x[r][k]*x[c][k]
    #pragma unroll
    for (int kk = 0; kk < 4; kk++) {
      half8 xr = *(const half8*)&xh[r * XS + kk * 32 + q * 8];
      half8 xc = *(const half8*)&xh[c * XS + kk * 32 + q * 8];
      Af[kk] = xr * xc;                        // 4x v_pk_mul_f16
    }

    f32x4 acc[8];
    #pragma unroll
    for (int n = 0; n < 8; n++) acc[n] = (f32x4){0.f, 0.f, 0.f, 0.f};
    #pragma unroll
    for (int kk = 0; kk < 4; kk++)
      #pragma unroll
      for (int n = 0; n < 8; n++)
        acc[n] = __builtin_amdgcn_mfma_f32_16x16x32_f16(Af[kk], Bf[n][kk], acc[n], 0, 0, 0);

    // fused bias + relu + gnn dot: D[row=q*4+rr][col=u], a = n*16+u
    float sc[4] = {0.f, 0.f, 0.f, 0.f};
    #pragma unroll
    for (int n = 0; n < 8; n++)
      #pragma unroll
      for (int rr = 0; rr < 4; rr++) {
        float fmv = fmaxf(acc[n][rr] + barr[n], 0.f);
        sc[rr] = fmaf(fmv, garr[n], sc[rr]);
      }
    #pragma unroll
    for (int rr = 0; rr < 4; rr++) sc[rr] = row_sum16(sc[rr]);
    if (u == 0)
      *(f32x4*)&scores_s[mt * 16 + q * 4] = (f32x4){sc[0], sc[1], sc[2], sc[3]};
  }
  __syncthreads();

  // ---------------- softmax over 528 scores ----------------
  float s0 = scores_s[tid];
  float s1 = scores_s[tid + 256];
  float s2 = (tid < 16) ? scores_s[tid + 512] : -3.4e38f;
  float m = fmaxf(fmaxf(s0, s1), s2);
  #pragma unroll
  for (int off = 32; off >= 1; off >>= 1) m = fmaxf(m, __shfl_xor(m, off, 64));
  if (lane == 0) red[wave] = m;
  __syncthreads();
  const float smax = fmaxf(fmaxf(red[0], red[1]), fmaxf(red[2], red[3]));

  float e0 = __expf(s0 - smax);
  float e1 = __expf(s1 - smax);
  float e2 = (tid < 16) ? __expf(s2 - smax) : 0.f;
  {
    unsigned int rc = rowcol[tid];
    attn2d[(rc & 255) * TS + ((rc >> 8) - (rc & 255) - 1)] = e0;
    rc = rowcol[tid + 256];
    attn2d[(rc & 255) * TS + ((rc >> 8) - (rc & 255) - 1)] = e1;
    if (tid < 16) {
      rc = rowcol[tid + 512];
      attn2d[(rc & 255) * TS + ((rc >> 8) - (rc & 255) - 1)] = e2;
    }
  }
  float lsum = e0 + e1 + e2;
  #pragma unroll
  for (int off = 32; off >= 1; off >>= 1) lsum += __shfl_xor(lsum, off, 64);
  if (lane == 0) red[4 + wave] = lsum;
  __syncthreads();
  const float Z = red[4] + red[5] + red[6] + red[7];

  // ---------------- epilogue: out = [gnn, 100 * attn @ inner], 2-way i-split ----------------
  {
    const int d = tid & 127;
    const int h = tid >> 7;          // i-range half
    float xcol[36];
    #pragma unroll
    for (int i = 0; i < FN; i++) xcol[i] = (float)xh[i * XS + d];
    xcol[33] = 0.f; xcol[34] = 0.f; xcol[35] = 0.f;

    float acc = 0.f;
    const int ibeg = h * 16, iend = ibeg + 16;   // i in [0,32)
    #pragma unroll
    for (int i = 0; i < 32; i++) {
      if (i < ibeg || i >= iend) continue;
      const int L = FN - 1 - i;                  // pairs (i, i+1+jj), jj < L
      const int nf4 = (L + 3) >> 2;
      float ti = 0.f;
      #pragma unroll
      for (int t = 0; t < 8; t++) {
        if (t >= nf4) break;
        f32x4 a4 = *(const f32x4*)&attn2d[i * TS + t * 4];  // pad entries are 0
        ti = fmaf(a4.x, xcol[i + 1 + t * 4 + 0], ti);
        ti = fmaf(a4.y, xcol[i + 1 + t * 4 + 1], ti);
        ti = fmaf(a4.z, xcol[i + 1 + t * 4 + 2], ti);
        ti = fmaf(a4.w, xcol[i + 1 + t * 4 + 3], ti);
      }
      acc = fmaf(xcol[i], ti, acc);
    }
    part[tid] = acc;
  }
  __syncthreads();
  if (tid < DN) {
    float tot = part[tid] + part[tid + 128];
    out[(size_t)b * (AN + DN) + AN + tid] = tot * (100.0f / Z);
  } else {
    const int a = tid - 128;
    out[(size_t)b * (AN + DN) + a] = gnn[(size_t)b * AN + a];
  }
}

extern "C" void kernel_launch(void* const* d_in, const int* in_sizes, int n_in,
                              void* d_out, int out_size, void* d_ws, size_t ws_size,
                              hipStream_t stream) {
  (void)n_in; (void)out_size; (void)d_ws; (void)ws_size;
  const float* gnn  = (const float*)d_in[0];
  const float* x    = (const float*)d_in[1];
  const float* W    = (const float*)d_in[2];
  const float* bias = (const float*)d_in[3];
  float* out = (float*)d_out;
  const int Bn = in_sizes[0] / AN;   // 1024
  afm_kernel<<<dim3(Bn), dim3(256), 0, stream>>>(gnn, x, W, bias, out);
}